// Round 12
// baseline (76.858 us; speedup 1.0000x reference)
//
#include <hip/hip_runtime.h>
#include <hip/hip_bf16.h>

// ---------------------------------------------------------------------------
// Diagonal-covariance GMM log-likelihoods as one bf16 MFMA GEMM + bias:
//   out[m,k] = sum_f [ x^2 * (-0.5/cov) + x * (mu/cov) ] + bias[k]
// GEMM: M=16384, N=512 (padded from 500), K2=2048 (interleaved x^2/x pairs)
//
// R11 = R10 structure at BM=64 for occupancy: 1024 blocks -> 3-4 blocks/CU
// (R6/R8/R10 all pinned at 65us with 2 barrier-coupled contexts/CU; staging
// mechanics didn't matter, context count is the invariant limiter).
//  - B: fragment-major W image, per-wave contiguous 1KB reg loads, ping-pong
//    one ahead, no LDS, no vmcnt drains (R7's regression = drain-0 + B-DMA
//    fill doubling; both absent here).
//  - A: 64x32f tile -> XOR-swizzled LDS dbuf (2x8KB); single reg set,
//    pack-then-refill (WAR-safe), 1 ahead. lgkm-only barriers. setprio on MFMA.
//  - acc 2x4 (32 AGPR), VGPR ~130 -> 3-4 waves/SIMD. LDS 32KB (epi overlay).
// ---------------------------------------------------------------------------

typedef __attribute__((ext_vector_type(8))) __bf16 bf16x8;
typedef __attribute__((ext_vector_type(4))) float  f32x4;

#define LOG_2PI 1.837877066409345339082f

constexpr int M_TOT = 16384;   // B*T
constexpr int F_DIM = 1024;
constexpr int K_GMM = 500;
constexpr int N_PAD = 512;

constexpr int BM  = 64;
constexpr int BN  = 128;
constexpr int BKF = 32;              // K-step in floats (=> 64 bf16 along K2)
constexpr int NIT = F_DIM / BKF;     // 32 K-steps

// pack (bf16(x*x), bf16(x)) into one dword: low16 = x^2 (even K2 slot), hi16 = x
__device__ __forceinline__ unsigned pack_sq_x(float x) {
    __hip_bfloat162 h = __float22bfloat162_rn(make_float2(x * x, x));
    union { __hip_bfloat162 h; unsigned u; } cv;
    cv.h = h;
    return cv.u;
}

// ---------------------------------------------------------------------------
// prep: build the FRAGMENT-MAJOR W image + fp32 bias. (unchanged from R10)
// Row k: tt=k>>7 (n_tile), wch=(k>>6)&1 (col-half), b=(k>>4)&3, lo=k&15.
// Row dword d: it=d>>5, c=(d>>4)&1, hi=(d>>2)&3, jj=d&3.
// Image dword addr = (((tt*2+wch)*32+it)*8 + (b*2+c))*256 + (hi*16+lo)*4 + jj.
// => per (tt,wch,it,frag) a contiguous 1KB block in exact lane order.
// Value: (bf16(-0.5/cov), bf16(mu/cov)); rows k>=500 zeroed, bias=0 there.
// ---------------------------------------------------------------------------
__global__ __launch_bounds__(256) void prep_w_kernel(
    const float* __restrict__ mu, const float* __restrict__ cov,
    unsigned* __restrict__ Wimg, float* __restrict__ bias)
{
    const int k = blockIdx.x;           // 0..511 (component row)
    const int t = threadIdx.x;
    const int tt  = k >> 7;
    const int wch = (k >> 6) & 1;
    const int b   = (k >> 4) & 3;
    const int lo  = k & 15;
    float sl = 0.f, sq = 0.f;
    #pragma unroll
    for (int j = 0; j < 4; ++j) {
        const int d  = t + j * 256;          // row dword index 0..1023
        const int it = d >> 5;
        const int c  = (d >> 4) & 1;
        const int hi = (d >> 2) & 3;
        const int jj = d & 3;
        const int dw = ((((tt * 2 + wch) * 32 + it) * 8) + (b * 2 + c)) * 256
                     + (hi * 16 + lo) * 4 + jj;
        if (k < K_GMM) {
            const float cv_ = cov[k * F_DIM + d];
            const float m_  = mu[k * F_DIM + d];
            const float ic  = 1.0f / cv_;
            __hip_bfloat162 h = __float22bfloat162_rn(make_float2(-0.5f * ic, m_ * ic));
            union { __hip_bfloat162 h; unsigned u; } cvt; cvt.h = h;
            Wimg[dw] = cvt.u;
            sl += logf(cv_);
            sq += m_ * m_ * ic;
        } else {
            Wimg[dw] = 0u;
        }
    }
    #pragma unroll
    for (int off = 32; off > 0; off >>= 1) {
        sl += __shfl_down(sl, off, 64);
        sq += __shfl_down(sq, off, 64);
    }
    __shared__ float red[8];
    if ((t & 63) == 0) { red[(t >> 6) * 2] = sl; red[(t >> 6) * 2 + 1] = sq; }
    __syncthreads();
    if (t == 0) {
        const float SL = red[0] + red[2] + red[4] + red[6];
        const float SQ = red[1] + red[3] + red[5] + red[7];
        bias[k] = (k < K_GMM)
                ? (-0.5f * (F_DIM * LOG_2PI) - 0.5f * SL - 0.5f * SQ) : 0.f;
    }
}

// ---------------------------------------------------------------------------
// GEMM: 64x128 tile, 4 waves (2x2, each 32x64), mfma_f32_16x16x32_bf16.
// LDS 32KB: A dbuf at {0,8K} (XOR-swizzled [64][64] bf16); epilogue overlay.
// B: per-wave contiguous 1KB fragment loads from the fragment-major image.
// 1024 blocks; m = bid&255, n = bid>>8 -> n-siblings 256 apart (same XCD).
// ---------------------------------------------------------------------------
__global__ __launch_bounds__(256, 2) void gemm_kernel(
    const float* __restrict__ X, const unsigned* __restrict__ Wimg,
    const float* __restrict__ bias, float* __restrict__ out)
{
    __shared__ __align__(16) char smem[32768];
    float* ep = reinterpret_cast<float*>(smem);   // 64x128 fp32 epilogue (32KB)

    const int bid    = blockIdx.x;
    const int m_base = (bid & 255) * BM;
    const int n_tile = bid >> 8;
    const int n_base = n_tile * BN;

    const int tid  = threadIdx.x;
    const int lane = tid & 63;
    const int wv   = tid >> 6;
    const int wr   = (wv >> 1) * 32;    // wave row block (0/32)
    const int wch  = wv & 1;            // wave col-half
    const int wc   = wch * 64;
    const int hi   = lane >> 4;         // 0..3
    const int lo   = lane & 15;
    const int lsw  = lo & 7;            // lane-constant fragment read swizzle

    const int sr = tid >> 2;            // A staging row 0..63
    const int sc = tid & 3;             // staging chunk pair

    const float4* Xv = reinterpret_cast<const float4*>(X);     // X row = 256 float4
    const bf16x8* Wf = reinterpret_cast<const bf16x8*>(Wimg);
    const int wbase = (n_tile * 2 + wch) * 32 * 8 * 64;        // bf16x8 units

    f32x4 acc[2][4];
    #pragma unroll
    for (int a = 0; a < 2; ++a)
        #pragma unroll
        for (int b = 0; b < 4; ++b)
            acc[a][b] = (f32x4){0.f, 0.f, 0.f, 0.f};

    auto loadA = [&](int itS, float4* ar) {           // 2 global float4 / thread
        #pragma unroll
        for (int j = 0; j < 2; ++j)
            ar[j] = Xv[(m_base + sr) * (F_DIM / 4) + itS * 8 + sc * 2 + j];
    };
    auto packA = [&](const float4* ar, int ab) {      // pack + swizzled ds_write
        unsigned short* Ad = reinterpret_cast<unsigned short*>(smem + ab * 8192);
        #pragma unroll
        for (int j = 0; j < 2; ++j) {
            const int chunk = (sc * 2 + j) ^ (sr & 7);
            uint4 wa;
            wa.x = pack_sq_x(ar[j].x);
            wa.y = pack_sq_x(ar[j].y);
            wa.z = pack_sq_x(ar[j].z);
            wa.w = pack_sq_x(ar[j].w);
            *reinterpret_cast<uint4*>(&Ad[sr * 64 + chunk * 8]) = wa;
        }
    };
    auto loadB = [&](int itS, bf16x8* br) {           // 8 contiguous 1KB wave-loads
        #pragma unroll
        for (int f = 0; f < 8; ++f)
            br[f] = Wf[wbase + (itS * 8 + f) * 64 + lane];
    };
    auto mfmas = [&](int ab, const bf16x8* br) {      // 4 ds_read_b128 + 16 MFMA
        const unsigned short* Asc =
            reinterpret_cast<const unsigned short*>(smem + ab * 8192);
        bf16x8 af[2];
        __builtin_amdgcn_s_setprio(1);
        #pragma unroll
        for (int c = 0; c < 2; ++c) {
            #pragma unroll
            for (int a = 0; a < 2; ++a) {
                const int row   = wr + a * 16 + lo;
                const int chunk = (c * 4 + hi) ^ lsw;
                af[a] = *reinterpret_cast<const bf16x8*>(&Asc[row * 64 + chunk * 8]);
            }
            #pragma unroll
            for (int a = 0; a < 2; ++a)
                #pragma unroll
                for (int b = 0; b < 4; ++b)
                    acc[a][b] = __builtin_amdgcn_mfma_f32_16x16x32_bf16(
                        af[a], br[b * 2 + c], acc[a][b], 0, 0, 0);
        }
        __builtin_amdgcn_s_setprio(0);
    };

    // ---- prologue ----
    float4 aA[2];
    bf16x8 b0[8], b1[8];
    loadA(0, aA);
    loadB(0, b0);
    loadB(1, b1);
    packA(aA, 0);          // auto-waits aA's loads only
    loadA(1, aA);          // A(1) in flight
    asm volatile("s_waitcnt lgkmcnt(0)" ::: "memory");
    __builtin_amdgcn_s_barrier();
    __builtin_amdgcn_sched_barrier(0);

    // ---- main loop: unroll-2; A single set pack-then-refill, B ping-pong ----
    for (int it = 0; it < NIT; it += 2) {
        // ===== even iter it: compute Abuf0 x b0 =====
        packA(aA, 1);                         // A(it+1) -> Abuf1 (always valid)
        if (it + 2 < NIT) loadA(it + 2, aA);  // refill after consume
        mfmas(0, b0);
        if (it + 2 < NIT) loadB(it + 2, b0);  // refill after consume
        asm volatile("s_waitcnt lgkmcnt(0)" ::: "memory");
        __builtin_amdgcn_s_barrier();
        __builtin_amdgcn_sched_barrier(0);

        // ===== odd iter it+1: compute Abuf1 x b1 =====
        if (it + 2 < NIT) packA(aA, 0);       // A(it+2) -> Abuf0
        if (it + 3 < NIT) loadA(it + 3, aA);
        mfmas(1, b1);
        if (it + 3 < NIT) loadB(it + 3, b1);
        asm volatile("s_waitcnt lgkmcnt(0)" ::: "memory");
        __builtin_amdgcn_s_barrier();
        __builtin_amdgcn_sched_barrier(0);
    }

    // ---- Epilogue: acc+bias -> 32KB LDS fp32 tile -> dense coalesced rows ----
    // (final loop barrier separates last ds_reads from ep overwrite)
    #pragma unroll
    for (int b = 0; b < 4; ++b) {
        const int col = wc + b * 16 + lo;
        const float bv = bias[n_base + col];
        #pragma unroll
        for (int a = 0; a < 2; ++a) {
            const int er = wr + a * 16 + hi * 4;  // D: col=lane&15, row=(lane>>4)*4+i
            #pragma unroll
            for (int i = 0; i < 4; ++i)
                ep[(er + i) * 128 + col] = acc[a][b][i] + bv;
        }
    }
    __syncthreads();

    const int ncols = (K_GMM - n_base < BN) ? (K_GMM - n_base) : BN;  // 128 or 116
    #pragma unroll
    for (int k = 0; k < 8; ++k) {
        const int f    = k * 256 + tid;   // float4 id in 64x32 grid
        const int row  = f >> 5;
        const int slot = f & 31;
        if (slot * 4 < ncols) {
            const float4 v = *reinterpret_cast<const float4*>(&ep[row * 128 + slot * 4]);
            *reinterpret_cast<float4*>(
                &out[(size_t)(m_base + row) * K_GMM + n_base + slot * 4]) = v;
        }
    }
}

extern "C" void kernel_launch(void* const* d_in, const int* in_sizes, int n_in,
                              void* d_out, int out_size, void* d_ws, size_t ws_size,
                              hipStream_t stream)
{
    (void)in_sizes; (void)n_in; (void)out_size; (void)ws_size;
    const float* X   = (const float*)d_in[0];
    const float* mu  = (const float*)d_in[1];
    const float* cov = (const float*)d_in[2];
    float* out = (float*)d_out;

    // workspace: W image = 512*1024 dwords (2 MiB), then bias[512] f32
    unsigned* Wimg = (unsigned*)d_ws;
    float*    bias = (float*)((char*)d_ws + (size_t)N_PAD * F_DIM * 4);

    prep_w_kernel<<<dim3(N_PAD), dim3(256), 0, stream>>>(mu, cov, Wimg, bias);
    gemm_kernel<<<dim3((M_TOT / BM) * (N_PAD / BN)), dim3(256), 0, stream>>>(X, Wimg, bias, out);
}

// Round 13
// 66.596 us; speedup vs baseline: 1.1541x; 1.1541x over previous
//
#include <hip/hip_runtime.h>
#include <hip/hip_bf16.h>

// ---------------------------------------------------------------------------
// Diagonal-covariance GMM log-likelihoods as one bf16 MFMA GEMM + bias:
//   out[m,k] = sum_f [ x^2 * (-0.5/cov) + x * (mu/cov) ] + bias[k]
// GEMM: M=16384, N=512 (padded from 500), K2=2048 (interleaved x^2/x pairs)
//
// R12: BARRIER-FREE main loop. R6/R8/R10 all pinned at ~65us profiled with
// ~20% MfmaUtil and no pipe >25%: block-wide barrier lockstep (every wave
// waits the slowest lgkm drain; phases align so pipes take turns idling).
// Fix: wave-autonomous tiles — each wave owns a private 32x128 output tile:
//  - A: wave-private LDS dbuf (2x4KB), wave stages its OWN 32 rows, reads
//    only its own region. Per-wave in-order DS completion + compiler-counted
//    lgkmcnt make it self-synced: NO s_barrier, NO vmcnt drains in the loop.
//  - B: fragment-major W image (R10 layout, both col-halves), in regs,
//    c-split (bc0/bc1), refilled right after consumption (reg-dep safe).
//  - A global loads 2 iters ahead (aA/aB ping-pong, static names).
//  - T5 setprio around MFMA clusters (waves genuinely de-phased now).
//  - One __syncthreads only before the epilogue LDS overlay re-partition;
//    epilogue is per-wave private (own 16KB region, self-synced).
// R11 lesson (3rd strike): BM=64 inflates FETCH — BM=128 fixed.
// ---------------------------------------------------------------------------

typedef __attribute__((ext_vector_type(8))) __bf16 bf16x8;
typedef __attribute__((ext_vector_type(4))) float  f32x4;

#define LOG_2PI 1.837877066409345339082f

constexpr int M_TOT = 16384;   // B*T
constexpr int F_DIM = 1024;
constexpr int K_GMM = 500;
constexpr int N_PAD = 512;

constexpr int BM  = 128;
constexpr int BN  = 128;
constexpr int BKF = 32;              // K-step in floats (=> 64 bf16 along K2)
constexpr int NIT = F_DIM / BKF;     // 32 K-steps

// pack (bf16(x*x), bf16(x)) into one dword: low16 = x^2 (even K2 slot), hi16 = x
__device__ __forceinline__ unsigned pack_sq_x(float x) {
    __hip_bfloat162 h = __float22bfloat162_rn(make_float2(x * x, x));
    union { __hip_bfloat162 h; unsigned u; } cv;
    cv.h = h;
    return cv.u;
}

// ---------------------------------------------------------------------------
// prep: build the FRAGMENT-MAJOR W image + fp32 bias. (unchanged from R10)
// Row k: tt=k>>7 (n_tile), wch=(k>>6)&1 (col-half), b=(k>>4)&3, lo=k&15.
// Row dword d: it=d>>5, c=(d>>4)&1, hi=(d>>2)&3, jj=d&3.
// Image dword addr = (((tt*2+wch)*32+it)*8 + (b*2+c))*256 + (hi*16+lo)*4 + jj.
// => per (tt,wch,it,frag) a contiguous 1KB block in exact lane order.
// Value: (bf16(-0.5/cov), bf16(mu/cov)); rows k>=500 zeroed, bias=0 there.
// ---------------------------------------------------------------------------
__global__ __launch_bounds__(256) void prep_w_kernel(
    const float* __restrict__ mu, const float* __restrict__ cov,
    unsigned* __restrict__ Wimg, float* __restrict__ bias)
{
    const int k = blockIdx.x;           // 0..511 (component row)
    const int t = threadIdx.x;
    const int tt  = k >> 7;
    const int wch = (k >> 6) & 1;
    const int b   = (k >> 4) & 3;
    const int lo  = k & 15;
    float sl = 0.f, sq = 0.f;
    #pragma unroll
    for (int j = 0; j < 4; ++j) {
        const int d  = t + j * 256;          // row dword index 0..1023
        const int it = d >> 5;
        const int c  = (d >> 4) & 1;
        const int hi = (d >> 2) & 3;
        const int jj = d & 3;
        const int dw = ((((tt * 2 + wch) * 32 + it) * 8) + (b * 2 + c)) * 256
                     + (hi * 16 + lo) * 4 + jj;
        if (k < K_GMM) {
            const float cv_ = cov[k * F_DIM + d];
            const float m_  = mu[k * F_DIM + d];
            const float ic  = 1.0f / cv_;
            __hip_bfloat162 h = __float22bfloat162_rn(make_float2(-0.5f * ic, m_ * ic));
            union { __hip_bfloat162 h; unsigned u; } cvt; cvt.h = h;
            Wimg[dw] = cvt.u;
            sl += logf(cv_);
            sq += m_ * m_ * ic;
        } else {
            Wimg[dw] = 0u;
        }
    }
    #pragma unroll
    for (int off = 32; off > 0; off >>= 1) {
        sl += __shfl_down(sl, off, 64);
        sq += __shfl_down(sq, off, 64);
    }
    __shared__ float red[8];
    if ((t & 63) == 0) { red[(t >> 6) * 2] = sl; red[(t >> 6) * 2 + 1] = sq; }
    __syncthreads();
    if (t == 0) {
        const float SL = red[0] + red[2] + red[4] + red[6];
        const float SQ = red[1] + red[3] + red[5] + red[7];
        bias[k] = (k < K_GMM)
                ? (-0.5f * (F_DIM * LOG_2PI) - 0.5f * SL - 0.5f * SQ) : 0.f;
    }
}

// ---------------------------------------------------------------------------
// GEMM: 128x128 tile, 4 waves, EACH wave owns 32 rows x 128 cols (2x8 frags).
// LDS 64KB: loop uses wave-private dbuf at wv*8192 + {0,4096}; epilogue
// overlays wave-private 16KB fp32 regions (one __syncthreads between).
// 512 blocks (2/CU); n-siblings of an m-tile are 128 apart in bid (same XCD).
// ---------------------------------------------------------------------------
__global__ __launch_bounds__(256, 2) void gemm_kernel(
    const float* __restrict__ X, const unsigned* __restrict__ Wimg,
    const float* __restrict__ bias, float* __restrict__ out)
{
    __shared__ __align__(16) char smem[65536];

    const int bid    = blockIdx.x;
    const int m_base = (bid & 127) * BM;
    const int n_tile = bid >> 7;
    const int n_base = n_tile * BN;

    const int tid  = threadIdx.x;
    const int lane = tid & 63;
    const int wv   = tid >> 6;
    const int wrb  = wv * 32;           // wave's private 32-row block
    const int hi   = lane >> 4;         // 0..3
    const int lo   = lane & 15;
    const int lsw  = lo & 7;            // lane-constant fragment read swizzle

    const int lr = lane >> 1;           // staging local row 0..31
    const int sh = lane & 1;            // staging half (chunks 0-3 / 4-7)
    const int sr = wrb + lr;            // staging row within tile

    const float4* Xv = reinterpret_cast<const float4*>(X);     // X row = 256 float4
    const bf16x8* Wf = reinterpret_cast<const bf16x8*>(Wimg);
    const int wb0 = (n_tile * 2 + 0) * 32 * 8 * 64;            // bf16x8 units
    const int wb1 = (n_tile * 2 + 1) * 32 * 8 * 64;

    f32x4 acc[2][8];
    #pragma unroll
    for (int a = 0; a < 2; ++a)
        #pragma unroll
        for (int b = 0; b < 8; ++b)
            acc[a][b] = (f32x4){0.f, 0.f, 0.f, 0.f};

    auto loadA = [&](int itS, float4* ar) {           // 4 global float4 / lane
        #pragma unroll
        for (int j = 0; j < 4; ++j)
            ar[j] = Xv[(size_t)(m_base + sr) * (F_DIM / 4) + itS * 8 + sh * 4 + j];
    };
    auto packA = [&](const float4* ar, int ab) {      // pack + swizzled ds_write
        unsigned short* Ad =
            reinterpret_cast<unsigned short*>(smem + wv * 8192 + ab * 4096);
        #pragma unroll
        for (int j = 0; j < 4; ++j) {
            const int chunk = (sh * 4 + j) ^ (lr & 7);
            uint4 wa;
            wa.x = pack_sq_x(ar[j].x);
            wa.y = pack_sq_x(ar[j].y);
            wa.z = pack_sq_x(ar[j].z);
            wa.w = pack_sq_x(ar[j].w);
            *reinterpret_cast<uint4*>(&Ad[lr * 64 + chunk * 8]) = wa;
        }
    };
    auto loadB = [&](int itS, int c, bf16x8* br) {    // 8 contiguous 1KB wave-loads
        #pragma unroll
        for (int b = 0; b < 4; ++b)
            br[b] = Wf[wb0 + (itS * 8 + b * 2 + c) * 64 + lane];
        #pragma unroll
        for (int b = 0; b < 4; ++b)
            br[4 + b] = Wf[wb1 + (itS * 8 + b * 2 + c) * 64 + lane];
    };
    auto mfma_c = [&](int ab, int c, const bf16x8* br) {  // 2 ds_read + 16 MFMA
        const unsigned short* Asc =
            reinterpret_cast<const unsigned short*>(smem + wv * 8192 + ab * 4096);
        bf16x8 af[2];
        #pragma unroll
        for (int a = 0; a < 2; ++a) {
            const int row   = a * 16 + lo;
            const int chunk = (c * 4 + hi) ^ lsw;
            af[a] = *reinterpret_cast<const bf16x8*>(&Asc[row * 64 + chunk * 8]);
        }
        __builtin_amdgcn_s_setprio(1);
        #pragma unroll
        for (int a = 0; a < 2; ++a)
            #pragma unroll
            for (int b = 0; b < 8; ++b)
                acc[a][b] = __builtin_amdgcn_mfma_f32_16x16x32_bf16(
                    af[a], br[b], acc[a][b], 0, 0, 0);
        __builtin_amdgcn_s_setprio(0);
    };

    // ---- prologue: no barrier — straight into the wave-private pipeline ----
    float4 aA[4], aB[4];
    bf16x8 bc0[8], bc1[8];
    loadA(0, aA);
    loadB(0, 0, bc0);
    loadB(0, 1, bc1);
    loadA(1, aB);
    packA(aA, 0);          // waits only aA's own loads (reg deps)

    // ---- main loop: unroll-2, zero barriers, zero drains ----
    for (int it = 0; it < NIT; it += 2) {
        // ===== even iter it: compute buf0; stage A(it+1)->buf1 =====
        if (it + 2 < NIT) loadA(it + 2, aA);      // aA free (packed last odd)
        packA(aB, 1);                              // A(it+1) -> buf1
        mfma_c(0, 0, bc0);
        if (it + 1 < NIT) loadB(it + 1, 0, bc0);   // refill after consume
        mfma_c(0, 1, bc1);
        if (it + 1 < NIT) loadB(it + 1, 1, bc1);

        // ===== odd iter it+1: compute buf1; stage A(it+2)->buf0 =====
        if (it + 3 < NIT) loadA(it + 3, aB);
        if (it + 2 < NIT) packA(aA, 0);            // A(it+2) -> buf0
        mfma_c(1, 0, bc0);
        if (it + 2 < NIT) loadB(it + 2, 0, bc0);
        mfma_c(1, 1, bc1);
        if (it + 2 < NIT) loadB(it + 2, 1, bc1);
    }

    // ---- Epilogue: ONE barrier (LDS re-partition), then wave-private ----
    __syncthreads();
    float* epw = reinterpret_cast<float*>(smem + wv * 16384);  // wave's 32x128 fp32
    #pragma unroll
    for (int b = 0; b < 8; ++b) {
        const int col = b * 16 + lo;
        const float bv = bias[n_base + col];
        #pragma unroll
        for (int a = 0; a < 2; ++a) {
            const int er = a * 16 + hi * 4;   // D: col=lane&15, row=(lane>>4)*4+i
            #pragma unroll
            for (int i = 0; i < 4; ++i)
                epw[(er + i) * 128 + col] = acc[a][b][i] + bv;
        }
    }
    // self-read own region (in-order DS + compiler lgkm waits; no barrier)
    const int ncols = (K_GMM - n_base < BN) ? (K_GMM - n_base) : BN;  // 128 or 116
    const int r2   = lane >> 5;    // 0..1
    const int slot = lane & 31;    // float4 slot within 128 cols
    if (slot * 4 < ncols) {
        #pragma unroll
        for (int rr = 0; rr < 16; ++rr) {
            const int row = rr * 2 + r2;
            const float4 v = *reinterpret_cast<const float4*>(&epw[row * 128 + slot * 4]);
            *reinterpret_cast<float4*>(
                &out[(size_t)(m_base + wrb + row) * K_GMM + n_base + slot * 4]) = v;
        }
    }
}

extern "C" void kernel_launch(void* const* d_in, const int* in_sizes, int n_in,
                              void* d_out, int out_size, void* d_ws, size_t ws_size,
                              hipStream_t stream)
{
    (void)in_sizes; (void)n_in; (void)out_size; (void)ws_size;
    const float* X   = (const float*)d_in[0];
    const float* mu  = (const float*)d_in[1];
    const float* cov = (const float*)d_in[2];
    float* out = (float*)d_out;

    // workspace: W image = 512*1024 dwords (2 MiB), then bias[512] f32
    unsigned* Wimg = (unsigned*)d_ws;
    float*    bias = (float*)((char*)d_ws + (size_t)N_PAD * F_DIM * 4);

    prep_w_kernel<<<dim3(N_PAD), dim3(256), 0, stream>>>(mu, cov, Wimg, bias);
    gemm_kernel<<<dim3((M_TOT / BM) * (N_PAD / BN)), dim3(256), 0, stream>>>(X, Wimg, bias, out);
}

// Round 14
// 66.446 us; speedup vs baseline: 1.1567x; 1.0022x over previous
//
#include <hip/hip_runtime.h>
#include <hip/hip_bf16.h>

// ---------------------------------------------------------------------------
// Diagonal-covariance GMM log-likelihoods as one bf16 MFMA GEMM + bias:
//   out[m,k] = sum_f [ x^2 * (-0.5/cov) + x * (mu/cov) ] + bias[k]
// GEMM: M=16384, N=512 (padded from 500), K2=2048 (interleaved x^2/x pairs)
//
// R13 = R10 economics with HALF the iterations: BKF=64 (16 K-steps).
// R6/R8/R10 (three staging schemes) all pinned at ~65us/20% MfmaUtil; R12
// (barrier-free) was worse -> barriers aren't the limiter; per-iteration
// fixed cost is the best remaining account. Changes:
//  - A: 128x128 bf16 tile/step, 64KB LDS dbuf, single reg set (pack-then-
//    refill, 1-iter flight), 4-bit XOR swizzle (row&15) — verified minimal
//    bank occupancy on write AND read.
//  - B: fragment-major image (unchanged prep); b0/b1 = the two K=32 halves
//    of the current step (64 VGPR total), refilled after consumption.
//  - 16 lgkm-only barriers (was 32). Single-pass 64KB epilogue.
// ---------------------------------------------------------------------------

typedef __attribute__((ext_vector_type(8))) __bf16 bf16x8;
typedef __attribute__((ext_vector_type(4))) float  f32x4;

#define LOG_2PI 1.837877066409345339082f

constexpr int M_TOT = 16384;   // B*T
constexpr int F_DIM = 1024;
constexpr int K_GMM = 500;
constexpr int N_PAD = 512;

constexpr int BM  = 128;
constexpr int BN  = 128;
constexpr int BKF = 64;              // K-step in floats (=> 128 bf16 along K2)
constexpr int NIT = F_DIM / BKF;     // 16 K-steps

// pack (bf16(x*x), bf16(x)) into one dword: low16 = x^2 (even K2 slot), hi16 = x
__device__ __forceinline__ unsigned pack_sq_x(float x) {
    __hip_bfloat162 h = __float22bfloat162_rn(make_float2(x * x, x));
    union { __hip_bfloat162 h; unsigned u; } cv;
    cv.h = h;
    return cv.u;
}

// ---------------------------------------------------------------------------
// prep: build the FRAGMENT-MAJOR W image + fp32 bias. (unchanged from R10)
// Row k: tt=k>>7 (n_tile), wch=(k>>6)&1 (col-half), b=(k>>4)&3, lo=k&15.
// Row dword d: blk=d>>5, c=(d>>4)&1, hi=(d>>2)&3, jj=d&3.
// Image dword addr = (((tt*2+wch)*32+blk)*8 + (b*2+c))*256 + (hi*16+lo)*4 + jj.
// => per (tt,wch,blk,frag) a contiguous 1KB block in exact lane order.
// gemm iteration k uses blocks 2k (b0) and 2k+1 (b1).
// Value: (bf16(-0.5/cov), bf16(mu/cov)); rows k>=500 zeroed, bias=0 there.
// ---------------------------------------------------------------------------
__global__ __launch_bounds__(256) void prep_w_kernel(
    const float* __restrict__ mu, const float* __restrict__ cov,
    unsigned* __restrict__ Wimg, float* __restrict__ bias)
{
    const int k = blockIdx.x;           // 0..511 (component row)
    const int t = threadIdx.x;
    const int tt  = k >> 7;
    const int wch = (k >> 6) & 1;
    const int b   = (k >> 4) & 3;
    const int lo  = k & 15;
    float sl = 0.f, sq = 0.f;
    #pragma unroll
    for (int j = 0; j < 4; ++j) {
        const int d   = t + j * 256;         // row dword index 0..1023
        const int blk = d >> 5;
        const int c   = (d >> 4) & 1;
        const int hi  = (d >> 2) & 3;
        const int jj  = d & 3;
        const int dw = ((((tt * 2 + wch) * 32 + blk) * 8) + (b * 2 + c)) * 256
                     + (hi * 16 + lo) * 4 + jj;
        if (k < K_GMM) {
            const float cv_ = cov[k * F_DIM + d];
            const float m_  = mu[k * F_DIM + d];
            const float ic  = 1.0f / cv_;
            __hip_bfloat162 h = __float22bfloat162_rn(make_float2(-0.5f * ic, m_ * ic));
            union { __hip_bfloat162 h; unsigned u; } cvt; cvt.h = h;
            Wimg[dw] = cvt.u;
            sl += logf(cv_);
            sq += m_ * m_ * ic;
        } else {
            Wimg[dw] = 0u;
        }
    }
    #pragma unroll
    for (int off = 32; off > 0; off >>= 1) {
        sl += __shfl_down(sl, off, 64);
        sq += __shfl_down(sq, off, 64);
    }
    __shared__ float red[8];
    if ((t & 63) == 0) { red[(t >> 6) * 2] = sl; red[(t >> 6) * 2 + 1] = sq; }
    __syncthreads();
    if (t == 0) {
        const float SL = red[0] + red[2] + red[4] + red[6];
        const float SQ = red[1] + red[3] + red[5] + red[7];
        bias[k] = (k < K_GMM)
                ? (-0.5f * (F_DIM * LOG_2PI) - 0.5f * SL - 0.5f * SQ) : 0.f;
    }
}

// ---------------------------------------------------------------------------
// GEMM: 128x128 tile, 4 waves (2x2, each 64x64), mfma_f32_16x16x32_bf16.
// LDS 64KB: A dbuf at {0,32K}, XOR-swizzled [128][128] bf16; epilogue overlay.
// Per iteration: 4 MFMA phases (s=0..3, K=32 each); b0 serves s=0,1 and
// b1 serves s=2,3 (c = s&1). 16 iterations, one lgkm-barrier each.
// 512 blocks (2/CU); n-siblings of an m-tile are 128 apart in bid (same XCD).
// ---------------------------------------------------------------------------
__global__ __launch_bounds__(256, 2) void gemm_kernel(
    const float* __restrict__ X, const unsigned* __restrict__ Wimg,
    const float* __restrict__ bias, float* __restrict__ out)
{
    __shared__ __align__(16) char smem[65536];

    const int bid    = blockIdx.x;
    const int m_base = (bid & 127) * BM;
    const int n_tile = bid >> 7;
    const int n_base = n_tile * BN;

    const int tid  = threadIdx.x;
    const int lane = tid & 63;
    const int wv   = tid >> 6;
    const int wr   = (wv >> 1) * 64;    // wave row block (0/64)
    const int wch  = wv & 1;            // wave col-half
    const int wc   = wch * 64;
    const int hi   = lane >> 4;         // 0..3
    const int lo   = lane & 15;

    const int sr = tid >> 1;            // A staging row 0..127
    const int sh = tid & 1;             // staging half (chunks 0-7 / 8-15)

    const float4* Xv = reinterpret_cast<const float4*>(X);     // X row = 256 float4
    const bf16x8* Wf = reinterpret_cast<const bf16x8*>(Wimg);
    const int wbase = (n_tile * 2 + wch) * 32 * 8 * 64;        // bf16x8 units

    f32x4 acc[4][4];
    #pragma unroll
    for (int a = 0; a < 4; ++a)
        #pragma unroll
        for (int b = 0; b < 4; ++b)
            acc[a][b] = (f32x4){0.f, 0.f, 0.f, 0.f};

    auto loadA = [&](int kS, float4* ar) {            // 8 global float4 / thread
        #pragma unroll
        for (int j = 0; j < 8; ++j)
            ar[j] = Xv[(size_t)(m_base + sr) * (F_DIM / 4) + kS * 16 + sh * 8 + j];
    };
    auto packA = [&](const float4* ar, int ab) {      // pack + swizzled ds_write
        unsigned short* Ad = reinterpret_cast<unsigned short*>(smem + ab * 32768);
        #pragma unroll
        for (int j = 0; j < 8; ++j) {
            const int chunk = (sh * 8 + j) ^ (sr & 15);
            uint4 wa;
            wa.x = pack_sq_x(ar[j].x);
            wa.y = pack_sq_x(ar[j].y);
            wa.z = pack_sq_x(ar[j].z);
            wa.w = pack_sq_x(ar[j].w);
            *reinterpret_cast<uint4*>(&Ad[sr * 128 + chunk * 8]) = wa;
        }
    };
    auto loadB_blk = [&](int blk, bf16x8* br) {       // 8 contiguous 1KB wave-loads
        #pragma unroll
        for (int f = 0; f < 8; ++f)
            br[f] = Wf[wbase + (blk * 8 + f) * 64 + lane];
    };
    auto phase = [&](int ab, int s, const bf16x8* br) {   // 4 ds_read + 16 MFMA
        const unsigned short* Asc =
            reinterpret_cast<const unsigned short*>(smem + ab * 32768);
        const int c     = s & 1;
        const int chunk = (s * 4 + hi) ^ lo;
        bf16x8 af[4];
        #pragma unroll
        for (int a = 0; a < 4; ++a) {
            const int row = wr + a * 16 + lo;
            af[a] = *reinterpret_cast<const bf16x8*>(&Asc[row * 128 + chunk * 8]);
        }
        __builtin_amdgcn_s_setprio(1);
        #pragma unroll
        for (int a = 0; a < 4; ++a)
            #pragma unroll
            for (int b = 0; b < 4; ++b)
                acc[a][b] = __builtin_amdgcn_mfma_f32_16x16x32_bf16(
                    af[a], br[b * 2 + c], acc[a][b], 0, 0, 0);
        __builtin_amdgcn_s_setprio(0);
    };

    // ---- prologue ----
    float4 aA[8];
    bf16x8 b0[8], b1[8];
    loadA(0, aA);
    loadB_blk(0, b0);
    loadB_blk(1, b1);
    packA(aA, 0);          // waits only aA's own loads (reg deps)
    loadA(1, aA);          // A(1) in flight (1-iter headroom)
    asm volatile("s_waitcnt lgkmcnt(0)" ::: "memory");
    __builtin_amdgcn_s_barrier();
    __builtin_amdgcn_sched_barrier(0);

    // ---- main loop: 16 iterations, one barrier each ----
    for (int k = 0; k < NIT; ++k) {
        const int ab = k & 1;
        if (k + 1 < NIT) {
            packA(aA, ab ^ 1);                 // A(k+1) -> other buffer
            if (k + 2 < NIT) loadA(k + 2, aA); // refill after consume
        }
        phase(ab, 0, b0);
        phase(ab, 1, b0);
        if (k + 1 < NIT) loadB_blk(2 * (k + 1), b0);      // refill b0
        phase(ab, 2, b1);
        phase(ab, 3, b1);
        if (k + 1 < NIT) loadB_blk(2 * (k + 1) + 1, b1);  // refill b1
        asm volatile("s_waitcnt lgkmcnt(0)" ::: "memory");
        __builtin_amdgcn_s_barrier();
        __builtin_amdgcn_sched_barrier(0);
    }

    // ---- Epilogue: single pass; acc+bias -> 64KB LDS fp32 -> dense rows ----
    // (final loop barrier separates last ds_reads from ep overwrite)
    float* ep = reinterpret_cast<float*>(smem);   // 128x128 fp32
    #pragma unroll
    for (int b = 0; b < 4; ++b) {
        const int col = wc + b * 16 + lo;
        const float bv = bias[n_base + col];
        #pragma unroll
        for (int a = 0; a < 4; ++a) {
            const int er = wr + a * 16 + hi * 4;  // D: col=lane&15, row=(lane>>4)*4+i
            #pragma unroll
            for (int i = 0; i < 4; ++i)
                ep[(er + i) * 128 + col] = acc[a][b][i] + bv;
        }
    }
    __syncthreads();

    const int ncols = (K_GMM - n_base < BN) ? (K_GMM - n_base) : BN;  // 128 or 116
    #pragma unroll
    for (int q = 0; q < 16; ++q) {
        const int f    = q * 256 + tid;   // float4 id in 128x32 grid
        const int row  = f >> 5;
        const int slot = f & 31;
        if (slot * 4 < ncols) {
            const float4 v = *reinterpret_cast<const float4*>(&ep[row * 128 + slot * 4]);
            *reinterpret_cast<float4*>(
                &out[(size_t)(m_base + row) * K_GMM + n_base + slot * 4]) = v;
        }
    }
}

extern "C" void kernel_launch(void* const* d_in, const int* in_sizes, int n_in,
                              void* d_out, int out_size, void* d_ws, size_t ws_size,
                              hipStream_t stream)
{
    (void)in_sizes; (void)n_in; (void)out_size; (void)ws_size;
    const float* X   = (const float*)d_in[0];
    const float* mu  = (const float*)d_in[1];
    const float* cov = (const float*)d_in[2];
    float* out = (float*)d_out;

    // workspace: W image = 512*1024 dwords (2 MiB), then bias[512] f32
    unsigned* Wimg = (unsigned*)d_ws;
    float*    bias = (float*)((char*)d_ws + (size_t)N_PAD * F_DIM * 4);

    prep_w_kernel<<<dim3(N_PAD), dim3(256), 0, stream>>>(mu, cov, Wimg, bias);
    gemm_kernel<<<dim3((M_TOT / BM) * (N_PAD / BN)), dim3(256), 0, stream>>>(X, Wimg, bias, out);
}

// Round 15
// 59.689 us; speedup vs baseline: 1.2876x; 1.1132x over previous
//
#include <hip/hip_runtime.h>
#include <hip/hip_bf16.h>

// ---------------------------------------------------------------------------
// Diagonal-covariance GMM log-likelihoods as one bf16 MFMA GEMM + bias:
//   out[m,k] = sum_f [ x^2 * (-0.5/cov) + x * (mu/cov) ] + bias[k]
// GEMM: M=16384, N=512 (padded from 500), K2=2048 (interleaved x^2/x pairs)
//
// R14: occupancy via register diet. R6-R13 refuted staging/barriers/iteration
// count as limiters; the invariant was 176 unified regs/wave -> 2 waves/SIMD.
// Now: 8 waves x 512 threads per 128x128 block, wave owns 32x64:
//   acc[2][4]=32 AGPR + B 32 VGPR (single set, refill-after-consume) +
//   A 8 VGPR -> ~110/wave; __launch_bounds__(512,4) caps at 128.
//   2 blocks/CU = 4 waves/SIMD (2x latency hiding).
// Structure = R10: B fragment-major in regs (col-half waves share via L1),
// A XOR-swizzled LDS dbuf (2x16KB), one lgkm-only barrier per iteration.
// ---------------------------------------------------------------------------

typedef __attribute__((ext_vector_type(8))) __bf16 bf16x8;
typedef __attribute__((ext_vector_type(4))) float  f32x4;

#define LOG_2PI 1.837877066409345339082f

constexpr int M_TOT = 16384;   // B*T
constexpr int F_DIM = 1024;
constexpr int K_GMM = 500;
constexpr int N_PAD = 512;

constexpr int BM  = 128;
constexpr int BN  = 128;
constexpr int BKF = 32;              // K-step in floats (=> 64 bf16 along K2)
constexpr int NIT = F_DIM / BKF;     // 32 K-steps

// pack (bf16(x*x), bf16(x)) into one dword: low16 = x^2 (even K2 slot), hi16 = x
__device__ __forceinline__ unsigned pack_sq_x(float x) {
    __hip_bfloat162 h = __float22bfloat162_rn(make_float2(x * x, x));
    union { __hip_bfloat162 h; unsigned u; } cv;
    cv.h = h;
    return cv.u;
}

// ---------------------------------------------------------------------------
// prep: build the FRAGMENT-MAJOR W image + fp32 bias. (unchanged from R10)
// Row k: tt=k>>7 (n_tile), wch=(k>>6)&1 (col-half), b=(k>>4)&3, lo=k&15.
// Row dword d: it=d>>5, c=(d>>4)&1, hi=(d>>2)&3, jj=d&3.
// Image dword addr = (((tt*2+wch)*32+it)*8 + (b*2+c))*256 + (hi*16+lo)*4 + jj.
// => per (tt,wch,it,frag) a contiguous 1KB block in exact lane order.
// Value: (bf16(-0.5/cov), bf16(mu/cov)); rows k>=500 zeroed, bias=0 there.
// ---------------------------------------------------------------------------
__global__ __launch_bounds__(256) void prep_w_kernel(
    const float* __restrict__ mu, const float* __restrict__ cov,
    unsigned* __restrict__ Wimg, float* __restrict__ bias)
{
    const int k = blockIdx.x;           // 0..511 (component row)
    const int t = threadIdx.x;
    const int tt  = k >> 7;
    const int wch = (k >> 6) & 1;
    const int b   = (k >> 4) & 3;
    const int lo  = k & 15;
    float sl = 0.f, sq = 0.f;
    #pragma unroll
    for (int j = 0; j < 4; ++j) {
        const int d  = t + j * 256;          // row dword index 0..1023
        const int it = d >> 5;
        const int c  = (d >> 4) & 1;
        const int hi = (d >> 2) & 3;
        const int jj = d & 3;
        const int dw = ((((tt * 2 + wch) * 32 + it) * 8) + (b * 2 + c)) * 256
                     + (hi * 16 + lo) * 4 + jj;
        if (k < K_GMM) {
            const float cv_ = cov[k * F_DIM + d];
            const float m_  = mu[k * F_DIM + d];
            const float ic  = 1.0f / cv_;
            __hip_bfloat162 h = __float22bfloat162_rn(make_float2(-0.5f * ic, m_ * ic));
            union { __hip_bfloat162 h; unsigned u; } cvt; cvt.h = h;
            Wimg[dw] = cvt.u;
            sl += logf(cv_);
            sq += m_ * m_ * ic;
        } else {
            Wimg[dw] = 0u;
        }
    }
    #pragma unroll
    for (int off = 32; off > 0; off >>= 1) {
        sl += __shfl_down(sl, off, 64);
        sq += __shfl_down(sq, off, 64);
    }
    __shared__ float red[8];
    if ((t & 63) == 0) { red[(t >> 6) * 2] = sl; red[(t >> 6) * 2 + 1] = sq; }
    __syncthreads();
    if (t == 0) {
        const float SL = red[0] + red[2] + red[4] + red[6];
        const float SQ = red[1] + red[3] + red[5] + red[7];
        bias[k] = (k < K_GMM)
                ? (-0.5f * (F_DIM * LOG_2PI) - 0.5f * SL - 0.5f * SQ) : 0.f;
    }
}

// ---------------------------------------------------------------------------
// GEMM: 128x128 tile, 8 waves (4 row-blocks x 2 col-halves, each 32x64).
// LDS 32KB: A dbuf at {0,16K}, XOR-swizzled [128][64] bf16; epilogue overlay.
// B: per-wave contiguous 1KB fragment loads (fragment-major image), single
// set refilled after consumption. One lgkm-only barrier per iteration.
// 512 blocks (2/CU, 4 waves/SIMD); n-siblings 128 apart in bid (same XCD).
// ---------------------------------------------------------------------------
__global__ __launch_bounds__(512, 4) void gemm_kernel(
    const float* __restrict__ X, const unsigned* __restrict__ Wimg,
    const float* __restrict__ bias, float* __restrict__ out)
{
    __shared__ __align__(16) char smem[32768];
    float* ep = reinterpret_cast<float*>(smem);   // 64x128 fp32 epilogue (32KB)

    const int bid    = blockIdx.x;
    const int m_base = (bid & 127) * BM;
    const int n_tile = bid >> 7;
    const int n_base = n_tile * BN;

    const int tid  = threadIdx.x;
    const int lane = tid & 63;
    const int wv   = tid >> 6;          // 0..7
    const int wr   = (wv >> 1) * 32;    // wave row block (0/32/64/96)
    const int wch  = wv & 1;            // wave col-half
    const int wc   = wch * 64;
    const int hi   = lane >> 4;         // 0..3
    const int lo   = lane & 15;
    const int lsw  = lo & 7;            // lane-constant fragment read swizzle

    const int sr = tid >> 2;            // A staging row 0..127
    const int sc = tid & 3;             // staging chunk pair (2 of 8)

    const float4* Xv = reinterpret_cast<const float4*>(X);     // X row = 256 float4
    const bf16x8* Wf = reinterpret_cast<const bf16x8*>(Wimg);
    const int wbase = (n_tile * 2 + wch) * 32 * 8 * 64;        // bf16x8 units

    f32x4 acc[2][4];
    #pragma unroll
    for (int a = 0; a < 2; ++a)
        #pragma unroll
        for (int b = 0; b < 4; ++b)
            acc[a][b] = (f32x4){0.f, 0.f, 0.f, 0.f};

    auto loadA = [&](int itS, float4* ar) {           // 2 global float4 / thread
        #pragma unroll
        for (int j = 0; j < 2; ++j)
            ar[j] = Xv[(size_t)(m_base + sr) * (F_DIM / 4) + itS * 8 + sc * 2 + j];
    };
    auto packA = [&](const float4* ar, int ab) {      // pack + swizzled ds_write
        unsigned short* Ad = reinterpret_cast<unsigned short*>(smem + ab * 16384);
        #pragma unroll
        for (int j = 0; j < 2; ++j) {
            const int chunk = (sc * 2 + j) ^ (sr & 7);
            uint4 wa;
            wa.x = pack_sq_x(ar[j].x);
            wa.y = pack_sq_x(ar[j].y);
            wa.z = pack_sq_x(ar[j].z);
            wa.w = pack_sq_x(ar[j].w);
            *reinterpret_cast<uint4*>(&Ad[sr * 64 + chunk * 8]) = wa;
        }
    };
    auto loadB = [&](int itS, bf16x8* br) {           // 8 contiguous 1KB wave-loads
        #pragma unroll
        for (int f = 0; f < 8; ++f)
            br[f] = Wf[wbase + (itS * 8 + f) * 64 + lane];
    };
    auto mfmas = [&](int ab, const bf16x8* br) {      // 4 ds_read_b128 + 16 MFMA
        const unsigned short* Asc =
            reinterpret_cast<const unsigned short*>(smem + ab * 16384);
        #pragma unroll
        for (int c = 0; c < 2; ++c) {
            bf16x8 af[2];
            #pragma unroll
            for (int a = 0; a < 2; ++a) {
                const int row   = wr + a * 16 + lo;
                const int chunk = (c * 4 + hi) ^ lsw;
                af[a] = *reinterpret_cast<const bf16x8*>(&Asc[row * 64 + chunk * 8]);
            }
            __builtin_amdgcn_s_setprio(1);
            #pragma unroll
            for (int a = 0; a < 2; ++a)
                #pragma unroll
                for (int b = 0; b < 4; ++b)
                    acc[a][b] = __builtin_amdgcn_mfma_f32_16x16x32_bf16(
                        af[a], br[b * 2 + c], acc[a][b], 0, 0, 0);
            __builtin_amdgcn_s_setprio(0);
        }
    };

    // ---- prologue ----
    float4 aA[2];
    bf16x8 bb[8];
    loadA(0, aA);
    loadB(0, bb);
    packA(aA, 0);          // waits only aA's own loads (reg deps)
    loadA(1, aA);          // A(1) in flight
    asm volatile("s_waitcnt lgkmcnt(0)" ::: "memory");
    __builtin_amdgcn_s_barrier();
    __builtin_amdgcn_sched_barrier(0);

    // ---- main loop: one lgkm-barrier per iteration ----
    for (int it = 0; it < NIT; ++it) {
        const int ab = it & 1;
        if (it + 1 < NIT) {
            packA(aA, ab ^ 1);                 // A(it+1) -> other buffer
            if (it + 2 < NIT) loadA(it + 2, aA);
        }
        mfmas(ab, bb);
        if (it + 1 < NIT) loadB(it + 1, bb);   // refill after consume
        asm volatile("s_waitcnt lgkmcnt(0)" ::: "memory");
        __builtin_amdgcn_s_barrier();
        __builtin_amdgcn_sched_barrier(0);
    }

    // ---- Epilogue: two 64-row passes; acc+bias -> LDS -> dense row writes ----
    // (final loop barrier separates last ds_reads from ep overwrite)
    const int ncols = (K_GMM - n_base < BN) ? (K_GMM - n_base) : BN;  // 128 or 116
    #pragma unroll
    for (int p = 0; p < 2; ++p) {
        if (p) __syncthreads();        // pass-0 reads done before pass-1 writes
        if ((wv >> 2) == p) {          // waves owning row-half p (4 waves) dump
            #pragma unroll
            for (int b = 0; b < 4; ++b) {
                const int col = wc + b * 16 + lo;
                const float bv = bias[n_base + col];
                const int er0 = ((wv >> 1) & 1) * 32;   // row within the 64-row half
                #pragma unroll
                for (int a = 0; a < 2; ++a) {
                    const int er = er0 + a * 16 + hi * 4;  // D: col=lane&15, row=(lane>>4)*4+i
                    #pragma unroll
                    for (int i = 0; i < 4; ++i)
                        ep[(er + i) * 128 + col] = acc[a][b][i] + bv;
                }
            }
        }
        __syncthreads();
        #pragma unroll
        for (int q = 0; q < 4; ++q) {
            const int f    = q * 512 + tid;   // float4 id in 64x32 grid
            const int row  = f >> 5;
            const int slot = f & 31;
            if (slot * 4 < ncols) {
                const float4 v = *reinterpret_cast<const float4*>(&ep[row * 128 + slot * 4]);
                *reinterpret_cast<float4*>(
                    &out[(size_t)(m_base + p * 64 + row) * K_GMM + n_base + slot * 4]) = v;
            }
        }
    }
}

extern "C" void kernel_launch(void* const* d_in, const int* in_sizes, int n_in,
                              void* d_out, int out_size, void* d_ws, size_t ws_size,
                              hipStream_t stream)
{
    (void)in_sizes; (void)n_in; (void)out_size; (void)ws_size;
    const float* X   = (const float*)d_in[0];
    const float* mu  = (const float*)d_in[1];
    const float* cov = (const float*)d_in[2];
    float* out = (float*)d_out;

    // workspace: W image = 512*1024 dwords (2 MiB), then bias[512] f32
    unsigned* Wimg = (unsigned*)d_ws;
    float*    bias = (float*)((char*)d_ws + (size_t)N_PAD * F_DIM * 4);

    prep_w_kernel<<<dim3(N_PAD), dim3(256), 0, stream>>>(mu, cov, Wimg, bias);
    gemm_kernel<<<dim3((M_TOT / BM) * (N_PAD / BN)), dim3(512), 0, stream>>>(X, Wimg, bias, out);
}